// Round 1
// baseline (897.660 us; speedup 1.0000x reference)
//
#include <hip/hip_runtime.h>
#include <math.h>

// Problem constants (B=2, H=32, S=16384, D=64), fp32 in/out.
#define BH_ 64
#define S_ 16384
#define D_ 64
#define LD_ 68                      // padded LDS row stride for p2 q-tile
#define KLD 68                      // padded kf stride in p1 (kills write-bank aliasing)
#define P1_CHUNKS 16
#define P1_ROWS (S_ / P1_CHUNKS)    // 1024 rows per phase-1 block
#define P1_STAGE 32                 // rows staged per iteration in p1
#define P2_CHUNKS 32
#define P2_ROWS (S_ / P2_CHUNKS)    // 512 rows per phase-2 block

__device__ __forceinline__ float elu1(float x) {
    // elu(x)+1 == x+1 (x>0) else exp(x)
    return x > 0.0f ? x + 1.0f : __expf(x);
}

#define FMA4(s, m, a) { (a).x += (s) * (m).x; (a).y += (s) * (m).y; (a).z += (s) * (m).z; (a).w += (s) * (m).w; }
#define ADD4(a, b)    { (a).x += (b).x; (a).y += (b).y; (a).z += (b).z; (a).w += (b).w; }

// async global->LDS, 16B per lane, wave-uniform LDS base + lane*16 linear dest
__device__ __forceinline__ void load_lds_16B(const float* g, float* l) {
    __builtin_amdgcn_global_load_lds(
        (const __attribute__((address_space(1))) unsigned int*)g,
        (__attribute__((address_space(3))) unsigned int*)l, 16, 0, 0);
}

// ---------------------------------------------------------------------------
// Phase 1: M[bh][dk][dv] = sum_s kf[s][dk] * v[s][dv];  z[bh][dk] = sum_s kf[s][dk]
// grid = (P1_CHUNKS, BH), block = 256 (4 waves).
// Each WAVE computes a full 64x64 partial M over its 8 rows of every 32-row
// stage; lane = (dk octet, dv octet) owns an 8x8 tile => 4 ds_read_b128 per
// s-row per wave (broadcast panels) feeding 64 FMAs/lane.
// V is staged via double-buffered global_load_lds (linear, stride 64);
// K is reg-prefetched, elu applied once at the LDS write.
// ---------------------------------------------------------------------------
__global__ __launch_bounds__(256, 4) void p1_kernel(const float* __restrict__ K,
                                                    const float* __restrict__ V,
                                                    float* __restrict__ Mg,
                                                    float* __restrict__ zg) {
    __shared__ float kf[P1_STAGE * KLD];        // 8704 B
    __shared__ float vf[2][P1_STAGE * D_];      // 2 x 8192 B (linear for global_load_lds)
    __shared__ float zpart[4][64];

    const int tid  = threadIdx.x;
    const int wid  = tid >> 6;       // wave id 0..3 (uniform per wave)
    const int lane = tid & 63;
    const int ki   = lane >> 3;      // dk octet [0,8)
    const int vj   = lane & 7;       // dv octet [0,8)

    const int bh    = blockIdx.y;
    const int chunk = blockIdx.x;
    const size_t base = ((size_t)bh * S_ + (size_t)chunk * P1_ROWS) * D_;
    const float* Kb = K + base;
    const float* Vb = V + base;

    // 8 dk-rows x 8 dv-cols accumulator (full 64x64 per wave)
    float4 acc[8][2];
    #pragma unroll
    for (int a = 0; a < 8; ++a) {
        acc[a][0] = make_float4(0.f, 0.f, 0.f, 0.f);
        acc[a][1] = make_float4(0.f, 0.f, 0.f, 0.f);
    }
    float zacc = 0.f;

    const int nstage = P1_ROWS / P1_STAGE;   // 32

    // ---- prologue: stage 0 ----
    {
        float4 k0 = *(const float4*)(Kb + tid * 4);          // rows 0..15
        float4 k1 = *(const float4*)(Kb + 1024 + tid * 4);   // rows 16..31
        float* vdst = &vf[0][wid * 512];
        load_lds_16B(Vb + wid * 512 + lane * 4, vdst);
        load_lds_16B(Vb + wid * 512 + 256 + lane * 4, vdst + 256);
        float4 e0, e1;
        e0.x = elu1(k0.x); e0.y = elu1(k0.y); e0.z = elu1(k0.z); e0.w = elu1(k0.w);
        e1.x = elu1(k1.x); e1.y = elu1(k1.y); e1.z = elu1(k1.z); e1.w = elu1(k1.w);
        *(float4*)&kf[(tid >> 4) * KLD + 4 * (tid & 15)] = e0;
        *(float4*)&kf[(16 + (tid >> 4)) * KLD + 4 * (tid & 15)] = e1;
        __syncthreads();   // drains V DMA (vmcnt) + kf writes (lgkm)
    }

    int buf = 0;
    for (int t = 0; t < nstage; ++t) {
        const int nt = t + 1;
        float4 nk0, nk1;
        if (nt < nstage) {
            // prefetch next stage: V -> other LDS buffer (async), K -> regs
            const float* Ks = Kb + (size_t)nt * P1_STAGE * D_;
            const float* Vs = Vb + (size_t)nt * P1_STAGE * D_;
            nk0 = *(const float4*)(Ks + tid * 4);
            nk1 = *(const float4*)(Ks + 1024 + tid * 4);
            float* vdst = &vf[buf ^ 1][wid * 512];
            load_lds_16B(Vs + wid * 512 + lane * 4, vdst);
            load_lds_16B(Vs + wid * 512 + 256 + lane * 4, vdst + 256);
        }

        // z partials: wave w sums rows [8w, 8w+8), one column per lane
        const float* kfw = &kf[(8 * wid) * KLD];
        #pragma unroll
        for (int j = 0; j < 8; ++j)
            zacc += kfw[j * KLD + lane];

        // rank-1 outer products over this wave's 8 rows
        const float* vfw = &vf[buf][(8 * wid) * D_];
        #pragma unroll 4
        for (int s = 0; s < 8; ++s) {
            float4 k0 = *(const float4*)&kfw[s * KLD + 8 * ki];
            float4 k1 = *(const float4*)&kfw[s * KLD + 8 * ki + 4];
            float4 v0 = *(const float4*)&vfw[s * D_ + 8 * vj];
            float4 v1 = *(const float4*)&vfw[s * D_ + 8 * vj + 4];
            FMA4(k0.x, v0, acc[0][0]); FMA4(k0.x, v1, acc[0][1]);
            FMA4(k0.y, v0, acc[1][0]); FMA4(k0.y, v1, acc[1][1]);
            FMA4(k0.z, v0, acc[2][0]); FMA4(k0.z, v1, acc[2][1]);
            FMA4(k0.w, v0, acc[3][0]); FMA4(k0.w, v1, acc[3][1]);
            FMA4(k1.x, v0, acc[4][0]); FMA4(k1.x, v1, acc[4][1]);
            FMA4(k1.y, v0, acc[5][0]); FMA4(k1.y, v1, acc[5][1]);
            FMA4(k1.z, v0, acc[6][0]); FMA4(k1.z, v1, acc[6][1]);
            FMA4(k1.w, v0, acc[7][0]); FMA4(k1.w, v1, acc[7][1]);
        }

        __syncthreads();   // all kf/vf reads done; prefetch (vmcnt) drained
        if (nt < nstage) {
            float4 e0, e1;
            e0.x = elu1(nk0.x); e0.y = elu1(nk0.y); e0.z = elu1(nk0.z); e0.w = elu1(nk0.w);
            e1.x = elu1(nk1.x); e1.y = elu1(nk1.y); e1.z = elu1(nk1.z); e1.w = elu1(nk1.w);
            *(float4*)&kf[(tid >> 4) * KLD + 4 * (tid & 15)] = e0;
            *(float4*)&kf[(16 + (tid >> 4)) * KLD + 4 * (tid & 15)] = e1;
        }
        buf ^= 1;
        __syncthreads();   // kf(t+1) visible
    }

    // z reduce across waves, one atomic per column
    zpart[wid][lane] = zacc;
    __syncthreads();
    if (tid < 64) {
        float z = zpart[0][tid] + zpart[1][tid] + zpart[2][tid] + zpart[3][tid];
        atomicAdd(&zg[bh * 64 + tid], z);
    }

    // M reduce: waves 1..3 feed wave 0 through a 16 KB scratch (reuses vf),
    // then wave 0 does the only global atomics (4096/block, same as before).
    float4* red = (float4*)&vf[0][0];   // [i4 0..15][lane 0..63], conflict-free
    for (int w = 1; w < 4; ++w) {
        if (wid == w) {
            #pragma unroll
            for (int a = 0; a < 8; ++a) {
                red[(2 * a + 0) * 64 + lane] = acc[a][0];
                red[(2 * a + 1) * 64 + lane] = acc[a][1];
            }
        }
        __syncthreads();
        if (wid == 0) {
            #pragma unroll
            for (int a = 0; a < 8; ++a) {
                float4 r0 = red[(2 * a + 0) * 64 + lane];
                float4 r1 = red[(2 * a + 1) * 64 + lane];
                ADD4(acc[a][0], r0);
                ADD4(acc[a][1], r1);
            }
        }
        __syncthreads();
    }
    if (wid == 0) {
        float* Mb = Mg + (size_t)bh * 4096 + (size_t)(8 * ki) * 64 + 8 * vj;
        #pragma unroll
        for (int a = 0; a < 8; ++a) {
            atomicAdd(&Mb[a * 64 + 0], acc[a][0].x);
            atomicAdd(&Mb[a * 64 + 1], acc[a][0].y);
            atomicAdd(&Mb[a * 64 + 2], acc[a][0].z);
            atomicAdd(&Mb[a * 64 + 3], acc[a][0].w);
            atomicAdd(&Mb[a * 64 + 4], acc[a][1].x);
            atomicAdd(&Mb[a * 64 + 5], acc[a][1].y);
            atomicAdd(&Mb[a * 64 + 6], acc[a][1].z);
            atomicAdd(&Mb[a * 64 + 7], acc[a][1].w);
        }
    }
}

// ---------------------------------------------------------------------------
// Phase 2: out[s][dv] = (qf[s] @ M)[dv] / (qf[s] . z)   — UNCHANGED this round
// grid = (P2_CHUNKS, BH), block = 256. Thread owns 4 s-rows x 4 dv-cols.
// ---------------------------------------------------------------------------
__global__ __launch_bounds__(256) void p2_kernel(const float* __restrict__ Q,
                                                 const float* __restrict__ Mg,
                                                 const float* __restrict__ zg,
                                                 float* __restrict__ Ob) {
    __shared__ float Ms[64 * 64];   // stride 64: reads are single-row -> conflict-free
    __shared__ float qs[64 * LD_];
    __shared__ float zs[64];

    const int tid = threadIdx.x;
    const int bh = blockIdx.y;
    const int chunk = blockIdx.x;
    const int si = tid >> 4;        // s tile [0,16): wave w -> si in [4w,4w+4)
    const int vj = tid & 15;        // dv tile [0,16)
    const int lane = tid & 63;

    // load this head's memory matrix + normalization into LDS
    #pragma unroll
    for (int k = 0; k < 4; ++k)
        *(float4*)&Ms[k * 1024 + tid * 4] =
            *(const float4*)&Mg[(size_t)bh * 4096 + k * 1024 + tid * 4];
    if (tid < 16)
        *(float4*)&zs[tid * 4] = *(const float4*)&zg[bh * 64 + tid * 4];

    const size_t base = ((size_t)bh * S_ + (size_t)chunk * P2_ROWS) * D_;
    const float* Qb = Q + base;
    float* Outb = Ob + base;

    const int drow = (tid >> 6) * 16 + (lane >> 2);  // denominator row (stage-local)
    const int seg = lane & 3;                        // 16-dk segment

    for (int s0 = 0; s0 < P2_ROWS; s0 += 64) {
        __syncthreads();  // also covers initial Ms/zs load
        // stage 64 qf rows
        #pragma unroll
        for (int k = 0; k < 4; ++k) {
            const int row = k * 16 + (tid >> 4);
            const int col = (tid & 15) * 4;
            float4 qv = *(const float4*)(Qb + (size_t)(s0 + row) * D_ + col);
            float4 qx;
            qx.x = elu1(qv.x); qx.y = elu1(qv.y); qx.z = elu1(qv.z); qx.w = elu1(qv.w);
            *(float4*)&qs[row * LD_ + col] = qx;
        }
        __syncthreads();

        // denominator: 4 lanes per row, each sums a 16-dk segment, butterfly-combine
        float dsum = 0.f;
        #pragma unroll
        for (int j = 0; j < 4; ++j) {
            float4 qq = *(const float4*)&qs[drow * LD_ + seg * 16 + j * 4];
            float4 zz = *(const float4*)&zs[seg * 16 + j * 4];
            dsum += qq.x * zz.x + qq.y * zz.y + qq.z * zz.z + qq.w * zz.w;
        }
        dsum += __shfl_xor(dsum, 1);
        dsum += __shfl_xor(dsum, 2);
        const float dinv = 1.0f / dsum;

        // matvec: 4 rows x 4 cols per thread; 8 b128 LDS reads + 64 FMA per 4-dk
        float4 a0 = {0.f,0.f,0.f,0.f}, a1 = a0, a2 = a0, a3 = a0;
        #pragma unroll 2
        for (int dk = 0; dk < 64; dk += 4) {
            float4 m0 = *(const float4*)&Ms[(dk + 0) * 64 + 4 * vj];
            float4 m1 = *(const float4*)&Ms[(dk + 1) * 64 + 4 * vj];
            float4 m2 = *(const float4*)&Ms[(dk + 2) * 64 + 4 * vj];
            float4 m3 = *(const float4*)&Ms[(dk + 3) * 64 + 4 * vj];
            float4 q0 = *(const float4*)&qs[(4 * si + 0) * LD_ + dk];
            float4 q1 = *(const float4*)&qs[(4 * si + 1) * LD_ + dk];
            float4 q2 = *(const float4*)&qs[(4 * si + 2) * LD_ + dk];
            float4 q3 = *(const float4*)&qs[(4 * si + 3) * LD_ + dk];
            FMA4(q0.x, m0, a0); FMA4(q0.y, m1, a0); FMA4(q0.z, m2, a0); FMA4(q0.w, m3, a0);
            FMA4(q1.x, m0, a1); FMA4(q1.y, m1, a1); FMA4(q1.z, m2, a1); FMA4(q1.w, m3, a1);
            FMA4(q2.x, m0, a2); FMA4(q2.y, m1, a2); FMA4(q2.z, m2, a2); FMA4(q2.w, m3, a2);
            FMA4(q3.x, m0, a3); FMA4(q3.y, m1, a3); FMA4(q3.z, m2, a3); FMA4(q3.w, m3, a3);
        }

        // scale by denominator reciprocal (shuffled from the lane that owns the row)
        #pragma unroll
        for (int r = 0; r < 4; ++r) {
            const float dv_ = __shfl(dinv, 16 * (si & 3) + 4 * r);
            float4 o = (r == 0) ? a0 : (r == 1) ? a1 : (r == 2) ? a2 : a3;
            o.x *= dv_; o.y *= dv_; o.z *= dv_; o.w *= dv_;
            *(float4*)(Outb + (size_t)(s0 + 4 * si + r) * D_ + 4 * vj) = o;
        }
    }
}

extern "C" void kernel_launch(void* const* d_in, const int* in_sizes, int n_in,
                              void* d_out, int out_size, void* d_ws, size_t ws_size,
                              hipStream_t stream) {
    const float* Q = (const float*)d_in[0];
    const float* K = (const float*)d_in[1];
    const float* V = (const float*)d_in[2];
    float* out = (float*)d_out;

    float* Mg = (float*)d_ws;                       // [BH][64][64]
    float* zg = Mg + (size_t)BH_ * 4096;            // [BH][64]
    const size_t init_bytes = ((size_t)BH_ * 4096 + (size_t)BH_ * 64) * sizeof(float);

    // ws is re-poisoned before every launch; zero the accumulators (capture-safe).
    hipMemsetAsync(d_ws, 0, init_bytes, stream);

    dim3 blk(256);
    dim3 g1(P1_CHUNKS, BH_);
    p1_kernel<<<g1, blk, 0, stream>>>(K, V, Mg, zg);

    dim3 g2(P2_CHUNKS, BH_);
    p2_kernel<<<g2, blk, 0, stream>>>(Q, Mg, zg, out);
}